// Round 1
// baseline (1037.546 us; speedup 1.0000x reference)
//
#include <hip/hip_runtime.h>
#include <math.h>

#define NDIM 128      // feature dim (D == H == 128)
#define GEMM_TM 64    // rows per block in GEMM
#define KT 32         // k-tile in GEMM

__device__ __forceinline__ float sigmoidf_(float x){ return 1.0f/(1.0f + __expf(-x)); }

// ---- degree / normalization ----
__global__ void deg_count_k(const int* __restrict__ dst, int* __restrict__ counts, int E){
  int e = blockIdx.x*blockDim.x + threadIdx.x;
  if(e < E) atomicAdd(&counts[dst[e]], 1);
}

__global__ void dinv_k(const int* __restrict__ counts, float* __restrict__ dinv, int N){
  int i = blockIdx.x*blockDim.x + threadIdx.x;
  if(i < N) dinv[i] = rsqrtf(1.0f + (float)counts[i]);
}

// ---- 3-kernel exclusive prefix scan over counts (chunk = 256) ----
__global__ void scan1_k(const int* __restrict__ counts, int* __restrict__ scanned,
                        int* __restrict__ chunksums, int N){
  __shared__ int lds[256];
  int t = threadIdx.x; int idx = blockIdx.x*256 + t;
  int x = (idx < N) ? counts[idx] : 0;
  lds[t] = x; __syncthreads();
  for(int o=1;o<256;o<<=1){
    int v = (t>=o) ? lds[t-o] : 0;
    __syncthreads();
    lds[t] += v;
    __syncthreads();
  }
  if(idx < N) scanned[idx] = lds[t];
  if(t == 255) chunksums[blockIdx.x] = lds[255];
}

__global__ void scan2_k(int* __restrict__ chunksums, int nchunks){
  __shared__ int lds[256];
  int t = threadIdx.x;
  int x = (t < nchunks) ? chunksums[t] : 0;
  lds[t] = x; __syncthreads();
  for(int o=1;o<256;o<<=1){
    int v = (t>=o) ? lds[t-o] : 0;
    __syncthreads();
    lds[t] += v;
    __syncthreads();
  }
  if(t < nchunks) chunksums[t] = lds[t] - x;   // exclusive
}

__global__ void scan3_k(const int* __restrict__ scanned, const int* __restrict__ counts,
                        const int* __restrict__ chunksums, int* __restrict__ row_start, int N){
  int i = blockIdx.x*blockDim.x + threadIdx.x;
  if(i < N) row_start[i] = scanned[i] - counts[i] + chunksums[i>>8];
}

__global__ void fill_k(const int* __restrict__ src, const int* __restrict__ dst,
                       const float* __restrict__ dinv, const int* __restrict__ row_start,
                       int* __restrict__ cursor, int* __restrict__ csr_src,
                       float* __restrict__ csr_norm, int E){
  int e = blockIdx.x*blockDim.x + threadIdx.x;
  if(e >= E) return;
  int d = dst[e], s = src[e];
  int pos = row_start[d] + atomicAdd(&cursor[d], 1);
  csr_src[pos] = s;
  csr_norm[pos] = dinv[s]*dinv[d];
}

// ---- dense GEMM: B[N,128] = A[N,128] @ W[128,128] ----
__global__ __launch_bounds__(256) void gemm_k(const float* __restrict__ A,
                                              const float* __restrict__ W,
                                              float* __restrict__ B, int N){
  __shared__ float Wl[KT][NDIM];      // 16 KB
  __shared__ float Hl[GEMM_TM][KT];   // 8 KB
  int t = threadIdx.x;
  int row0 = blockIdx.x * GEMM_TM;
  int colg = (t & 31) * 4;            // 4 consecutive output cols
  int rowg = (t >> 5) * 8;            // 8 rows per thread
  float acc[8][4];
  #pragma unroll
  for(int r=0;r<8;r++)
    #pragma unroll
    for(int c=0;c<4;c++) acc[r][c]=0.f;

  for(int k0=0;k0<NDIM;k0+=KT){
    #pragma unroll
    for(int i=0;i<4;i++){             // W tile: 4096 floats
      int lin = (t + i*256)*4;
      int kk = lin >> 7, col = lin & 127;
      *(float4*)&Wl[kk][col] = *(const float4*)&W[(k0+kk)*NDIM + col];
    }
    #pragma unroll
    for(int i=0;i<2;i++){             // H tile: 2048 floats
      int lin = (t + i*256)*4;
      int r = lin >> 5, kk = lin & 31;
      int grow = row0 + r;
      float4 v = make_float4(0.f,0.f,0.f,0.f);
      if(grow < N) v = *(const float4*)&A[grow*NDIM + k0 + kk];
      *(float4*)&Hl[r][kk] = v;
    }
    __syncthreads();
    #pragma unroll
    for(int kk=0; kk<KT; kk+=4){
      float4 wv0 = *(float4*)&Wl[kk+0][colg];
      float4 wv1 = *(float4*)&Wl[kk+1][colg];
      float4 wv2 = *(float4*)&Wl[kk+2][colg];
      float4 wv3 = *(float4*)&Wl[kk+3][colg];
      #pragma unroll
      for(int r=0;r<8;r++){
        float4 hv = *(float4*)&Hl[rowg + r][kk];
        acc[r][0] += hv.x*wv0.x + hv.y*wv1.x + hv.z*wv2.x + hv.w*wv3.x;
        acc[r][1] += hv.x*wv0.y + hv.y*wv1.y + hv.z*wv2.y + hv.w*wv3.y;
        acc[r][2] += hv.x*wv0.z + hv.y*wv1.z + hv.z*wv2.z + hv.w*wv3.z;
        acc[r][3] += hv.x*wv0.w + hv.y*wv1.w + hv.z*wv2.w + hv.w*wv3.w;
      }
    }
    __syncthreads();
  }
  #pragma unroll
  for(int r=0;r<8;r++){
    int grow = row0 + rowg + r;
    if(grow < N) *(float4*)&B[grow*NDIM + colg] = *(float4*)&acc[r][0];
  }
}

// ---- CSR gather aggregation: hC[i] = sum_e norm*hB[src] + dinv[i]^2*hB[i] + b ----
__global__ void agg_k(const float* __restrict__ hB, const float* __restrict__ dinv,
                      const int* __restrict__ row_start, const int* __restrict__ counts,
                      const int* __restrict__ csr_src, const float* __restrict__ csr_norm,
                      const float* __restrict__ bias, float* __restrict__ hC, int N){
  int i = blockIdx.x;
  if(i >= N) return;
  int t = threadIdx.x;                // 64 threads, lane = feature pair
  int rs = row_start[i], cnt = counts[i];
  float2 acc = make_float2(0.f, 0.f);
  for(int j=rs; j<rs+cnt; j++){
    int s = csr_src[j];
    float nm = csr_norm[j];
    float2 v = *(const float2*)&hB[s*NDIM + t*2];
    acc.x += nm*v.x; acc.y += nm*v.y;
  }
  float di = dinv[i]; float sn = di*di;
  float2 hv = *(const float2*)&hB[i*NDIM + t*2];
  float2 bv = *(const float2*)&bias[t*2];
  float2 o;
  o.x = acc.x + sn*hv.x + bv.x;
  o.y = acc.y + sn*hv.y + bv.y;
  *(float2*)&hC[i*NDIM + t*2] = o;
}

// ---- BN column stats (sum, sumsq) ----
__global__ void stats_k(const float* __restrict__ h, float* __restrict__ sums,
                        float* __restrict__ sumsq, int N){
  __shared__ float ls[256], lq[256];
  int t = threadIdx.x;
  int f = t & 127, half = t >> 7;
  int rowsPerBlock = (N + gridDim.x - 1)/gridDim.x;
  int r0 = blockIdx.x * rowsPerBlock;
  int r1 = min(N, r0 + rowsPerBlock);
  float s=0.f, q=0.f;
  for(int r=r0+half; r<r1; r+=2){
    float v = h[r*NDIM + f];
    s += v; q += v*v;
  }
  ls[t]=s; lq[t]=q; __syncthreads();
  if(t < 128){
    s = ls[t] + ls[t+128];
    q = lq[t] + lq[t+128];
    atomicAdd(&sums[f], s);
    atomicAdd(&sumsq[f], q);
  }
}

// ---- BN normalize + sigmoid ----
__global__ void bnapply_k(const float* __restrict__ h, const float* __restrict__ sums,
                          const float* __restrict__ sumsq, const float* __restrict__ g,
                          const float* __restrict__ be, float* __restrict__ out, int N){
  int idx = (blockIdx.x*blockDim.x + threadIdx.x)*4;
  if(idx >= N*NDIM) return;
  int f = idx & 127;
  float invN = 1.0f/(float)N;
  float4 v = *(const float4*)&h[idx];
  float4 o;
  {
    float m = sums[f+0]*invN; float var = fmaxf(sumsq[f+0]*invN - m*m, 0.f);
    o.x = sigmoidf_((v.x - m)*rsqrtf(var+1e-5f)*g[f+0] + be[f+0]);
  }
  {
    float m = sums[f+1]*invN; float var = fmaxf(sumsq[f+1]*invN - m*m, 0.f);
    o.y = sigmoidf_((v.y - m)*rsqrtf(var+1e-5f)*g[f+1] + be[f+1]);
  }
  {
    float m = sums[f+2]*invN; float var = fmaxf(sumsq[f+2]*invN - m*m, 0.f);
    o.z = sigmoidf_((v.z - m)*rsqrtf(var+1e-5f)*g[f+2] + be[f+2]);
  }
  {
    float m = sums[f+3]*invN; float var = fmaxf(sumsq[f+3]*invN - m*m, 0.f);
    o.w = sigmoidf_((v.w - m)*rsqrtf(var+1e-5f)*g[f+3] + be[f+3]);
  }
  *(float4*)&out[idx] = o;
}

// ---- pooling ----
__global__ void bcnt_k(const int* __restrict__ batch, int* __restrict__ bcnt, int N){
  int i = blockIdx.x*blockDim.x + threadIdx.x;
  if(i < N) atomicAdd(&bcnt[batch[i]], 1);
}

__global__ void pool_k(const float* __restrict__ h, const int* __restrict__ batch,
                       float* __restrict__ out, int N){
  int f = threadIdx.x;                // 128
  int r0 = blockIdx.x*128;
  if(r0 >= N) return;
  int r1 = min(N, r0+128);
  float acc = 0.f; int cur = batch[r0];
  for(int r=r0; r<r1; r++){
    int g = batch[r];
    if(g != cur){ atomicAdd(&out[cur*NDIM+f], acc); acc = 0.f; cur = g; }
    acc += h[r*NDIM+f];
  }
  atomicAdd(&out[cur*NDIM+f], acc);
}

__global__ void div_k(float* __restrict__ out, const int* __restrict__ bcnt, int total){
  int i = blockIdx.x*blockDim.x + threadIdx.x;
  if(i < total) out[i] /= fmaxf((float)bcnt[i>>7], 1.0f);
}

extern "C" void kernel_launch(void* const* d_in, const int* in_sizes, int n_in,
                              void* d_out, int out_size, void* d_ws, size_t ws_size,
                              hipStream_t stream){
  const float* x     = (const float*)d_in[0];
  const int*   ei    = (const int*)d_in[1];
  const int*   batch = (const int*)d_in[3];
  const float* W [3] = {(const float*)d_in[4], (const float*)d_in[6], (const float*)d_in[8]};
  const float* bi[3] = {(const float*)d_in[5], (const float*)d_in[7], (const float*)d_in[9]};
  const float* gg[3] = {(const float*)d_in[10], (const float*)d_in[12], (const float*)d_in[14]};
  const float* bb[3] = {(const float*)d_in[11], (const float*)d_in[13], (const float*)d_in[15]};

  int N = in_sizes[0] / NDIM;
  int E = in_sizes[1] / 2;
  const int* src = ei;
  const int* dst = ei + E;

  // workspace bump allocator (256 B aligned)
  char* p = (char*)d_ws;
  auto alloc = [&](size_t bytes)->void*{
    void* r = (void*)p; p += (bytes + 255) & ~(size_t)255; return r;
  };
  float* hA        = (float*)alloc((size_t)N*NDIM*4);
  float* hB        = (float*)alloc((size_t)N*NDIM*4);
  float* hC        = (float*)alloc((size_t)N*NDIM*4);
  int*   counts    = (int*)  alloc((size_t)N*4);
  int*   cursor    = (int*)  alloc((size_t)N*4);
  int*   scanned   = (int*)  alloc((size_t)N*4);
  int*   chunksums = (int*)  alloc(256*4);
  int*   row_start = (int*)  alloc((size_t)N*4);
  float* dinv      = (float*)alloc((size_t)N*4);
  int*   csr_src   = (int*)  alloc((size_t)E*4);
  float* csr_norm  = (float*)alloc((size_t)E*4);
  float* sums      = (float*)alloc(3*128*4);
  float* sumsq     = (float*)alloc(3*128*4);
  int*   bcnt      = (int*)  alloc(64*4);

  hipMemsetAsync(counts, 0, (size_t)N*4, stream);
  hipMemsetAsync(cursor, 0, (size_t)N*4, stream);
  hipMemsetAsync(sums,  0, 3*128*4, stream);
  hipMemsetAsync(sumsq, 0, 3*128*4, stream);
  hipMemsetAsync(bcnt,  0, 64*4, stream);
  hipMemsetAsync(d_out, 0, (size_t)out_size*4, stream);

  deg_count_k<<<(E+255)/256, 256, 0, stream>>>(dst, counts, E);
  dinv_k<<<(N+255)/256, 256, 0, stream>>>(counts, dinv, N);

  int nchunks = (N+255)/256;     // 196 <= 256
  scan1_k<<<nchunks, 256, 0, stream>>>(counts, scanned, chunksums, N);
  scan2_k<<<1, 256, 0, stream>>>(chunksums, nchunks);
  scan3_k<<<(N+255)/256, 256, 0, stream>>>(scanned, counts, chunksums, row_start, N);
  fill_k<<<(E+255)/256, 256, 0, stream>>>(src, dst, dinv, row_start, cursor, csr_src, csr_norm, E);

  const float* hin = x;
  for(int l=0; l<3; l++){
    gemm_k<<<(N+GEMM_TM-1)/GEMM_TM, 256, 0, stream>>>(hin, W[l], hB, N);
    agg_k<<<N, 64, 0, stream>>>(hB, dinv, row_start, counts, csr_src, csr_norm, bi[l], hC, N);
    stats_k<<<128, 256, 0, stream>>>(hC, sums + l*128, sumsq + l*128, N);
    bnapply_k<<<((N*NDIM/4)+255)/256, 256, 0, stream>>>(hC, sums + l*128, sumsq + l*128,
                                                        gg[l], bb[l], hA, N);
    hin = hA;
  }

  bcnt_k<<<(N+255)/256, 256, 0, stream>>>(batch, bcnt, N);
  pool_k<<<(N+127)/128, 128, 0, stream>>>(hA, batch, (float*)d_out, N);
  div_k<<<(out_size+255)/256, 256, 0, stream>>>((float*)d_out, bcnt, out_size);
}

// Round 2
// 804.283 us; speedup vs baseline: 1.2900x; 1.2900x over previous
//
#include <hip/hip_runtime.h>
#include <math.h>

#define NDIM 128      // feature dim (D == H == 128)
#define GEMM_TM 64    // rows per block in GEMM
#define KT 32         // k-tile in GEMM

__device__ __forceinline__ float sigmoidf_(float x){ return 1.0f/(1.0f + __expf(-x)); }

// ---- degree / normalization ----
__global__ void deg_count_k(const int* __restrict__ dst, int* __restrict__ counts, int E){
  int e = blockIdx.x*blockDim.x + threadIdx.x;
  if(e < E) atomicAdd(&counts[dst[e]], 1);
}

__global__ void dinv_k(const int* __restrict__ counts, float* __restrict__ dinv, int N){
  int i = blockIdx.x*blockDim.x + threadIdx.x;
  if(i < N) dinv[i] = rsqrtf(1.0f + (float)counts[i]);
}

// ---- 3-kernel exclusive prefix scan over counts (chunk = 256) ----
__global__ void scan1_k(const int* __restrict__ counts, int* __restrict__ scanned,
                        int* __restrict__ chunksums, int N){
  __shared__ int lds[256];
  int t = threadIdx.x; int idx = blockIdx.x*256 + t;
  int x = (idx < N) ? counts[idx] : 0;
  lds[t] = x; __syncthreads();
  for(int o=1;o<256;o<<=1){
    int v = (t>=o) ? lds[t-o] : 0;
    __syncthreads();
    lds[t] += v;
    __syncthreads();
  }
  if(idx < N) scanned[idx] = lds[t];
  if(t == 255) chunksums[blockIdx.x] = lds[255];
}

__global__ void scan2_k(int* __restrict__ chunksums, int nchunks){
  __shared__ int lds[256];
  int t = threadIdx.x;
  int x = (t < nchunks) ? chunksums[t] : 0;
  lds[t] = x; __syncthreads();
  for(int o=1;o<256;o<<=1){
    int v = (t>=o) ? lds[t-o] : 0;
    __syncthreads();
    lds[t] += v;
    __syncthreads();
  }
  if(t < nchunks) chunksums[t] = lds[t] - x;   // exclusive
}

__global__ void scan3_k(const int* __restrict__ scanned, const int* __restrict__ counts,
                        const int* __restrict__ chunksums, int* __restrict__ row_start, int N){
  int i = blockIdx.x*blockDim.x + threadIdx.x;
  if(i < N) row_start[i] = scanned[i] - counts[i] + chunksums[i>>8];
}

__global__ void fill_k(const int* __restrict__ src, const int* __restrict__ dst,
                       const float* __restrict__ dinv, const int* __restrict__ row_start,
                       int* __restrict__ cursor, int* __restrict__ csr_src,
                       float* __restrict__ csr_norm, int E){
  int e = blockIdx.x*blockDim.x + threadIdx.x;
  if(e >= E) return;
  int d = dst[e], s = src[e];
  int pos = row_start[d] + atomicAdd(&cursor[d], 1);
  csr_src[pos] = s;
  csr_norm[pos] = dinv[s]*dinv[d];
}

// ---- graph boundaries via binary search (batch is sorted) ----
__global__ void bounds_k(const int* __restrict__ batch, int* __restrict__ bound, int N, int G){
  int g = threadIdx.x;
  if(g > G) return;
  int lo = 0, hi = N;
  while(lo < hi){ int mid = (lo+hi)>>1; if(batch[mid] < g) lo = mid+1; else hi = mid; }
  bound[g] = lo;
}

// ---- dense GEMM: B[N,128] = bnsig(A)[N,128] @ W[128,128], optional fused BN+sigmoid on A ----
__global__ __launch_bounds__(256) void gemm_k(const float* __restrict__ A,
                                              const float* __restrict__ W,
                                              float* __restrict__ B,
                                              const float* __restrict__ scale,  // null => raw A
                                              const float* __restrict__ shift,
                                              int N){
  __shared__ float Wl[KT][NDIM];      // 16 KB
  __shared__ float Hl[GEMM_TM][KT];   // 8 KB
  int t = threadIdx.x;
  int row0 = blockIdx.x * GEMM_TM;
  int colg = (t & 31) * 4;            // 4 consecutive output cols
  int rowg = (t >> 5) * 8;            // 8 rows per thread
  bool bn = (scale != nullptr);
  float acc[8][4];
  #pragma unroll
  for(int r=0;r<8;r++)
    #pragma unroll
    for(int c=0;c<4;c++) acc[r][c]=0.f;

  for(int k0=0;k0<NDIM;k0+=KT){
    #pragma unroll
    for(int i=0;i<4;i++){             // W tile: 4096 floats
      int lin = (t + i*256)*4;
      int kk = lin >> 7, col = lin & 127;
      *(float4*)&Wl[kk][col] = *(const float4*)&W[(k0+kk)*NDIM + col];
    }
    #pragma unroll
    for(int i=0;i<2;i++){             // H tile: 2048 floats
      int lin = (t + i*256)*4;
      int r = lin >> 5, kk = lin & 31;
      int grow = row0 + r;
      float4 v = make_float4(0.f,0.f,0.f,0.f);
      if(grow < N){
        v = *(const float4*)&A[grow*NDIM + k0 + kk];
        if(bn){
          float4 sc = *(const float4*)&scale[k0+kk];
          float4 sh = *(const float4*)&shift[k0+kk];
          v.x = sigmoidf_(v.x*sc.x + sh.x);
          v.y = sigmoidf_(v.y*sc.y + sh.y);
          v.z = sigmoidf_(v.z*sc.z + sh.z);
          v.w = sigmoidf_(v.w*sc.w + sh.w);
        }
      }
      *(float4*)&Hl[r][kk] = v;
    }
    __syncthreads();
    #pragma unroll
    for(int kk=0; kk<KT; kk+=4){
      float4 wv0 = *(float4*)&Wl[kk+0][colg];
      float4 wv1 = *(float4*)&Wl[kk+1][colg];
      float4 wv2 = *(float4*)&Wl[kk+2][colg];
      float4 wv3 = *(float4*)&Wl[kk+3][colg];
      #pragma unroll
      for(int r=0;r<8;r++){
        float4 hv = *(float4*)&Hl[rowg + r][kk];
        acc[r][0] += hv.x*wv0.x + hv.y*wv1.x + hv.z*wv2.x + hv.w*wv3.x;
        acc[r][1] += hv.x*wv0.y + hv.y*wv1.y + hv.z*wv2.y + hv.w*wv3.y;
        acc[r][2] += hv.x*wv0.z + hv.y*wv1.z + hv.z*wv2.z + hv.w*wv3.z;
        acc[r][3] += hv.x*wv0.w + hv.y*wv1.w + hv.z*wv2.w + hv.w*wv3.w;
      }
    }
    __syncthreads();
  }
  #pragma unroll
  for(int r=0;r<8;r++){
    int grow = row0 + rowg + r;
    if(grow < N) *(float4*)&B[grow*NDIM + colg] = *(float4*)&acc[r][0];
  }
}

// ---- CSR gather aggregation: hC[i] = sum_e norm*hB[src] + dinv[i]^2*hB[i] + b ----
__global__ void agg_k(const float* __restrict__ hB, const float* __restrict__ dinv,
                      const int* __restrict__ row_start, const int* __restrict__ counts,
                      const int* __restrict__ csr_src, const float* __restrict__ csr_norm,
                      const float* __restrict__ bias, float* __restrict__ hC, int N){
  int i = blockIdx.x;
  if(i >= N) return;
  int t = threadIdx.x;                // 64 threads, lane = feature pair
  int rs = row_start[i], cnt = counts[i];
  float2 acc = make_float2(0.f, 0.f);
  int j = rs;
  for(; j+1 < rs+cnt; j += 2){        // 2-way unroll: overlap the two row loads
    int s0 = csr_src[j],   s1 = csr_src[j+1];
    float n0 = csr_norm[j], n1 = csr_norm[j+1];
    float2 v0 = *(const float2*)&hB[s0*NDIM + t*2];
    float2 v1 = *(const float2*)&hB[s1*NDIM + t*2];
    acc.x += n0*v0.x + n1*v1.x;
    acc.y += n0*v0.y + n1*v1.y;
  }
  if(j < rs+cnt){
    int s = csr_src[j]; float nm = csr_norm[j];
    float2 v = *(const float2*)&hB[s*NDIM + t*2];
    acc.x += nm*v.x; acc.y += nm*v.y;
  }
  float di = dinv[i]; float sn = di*di;
  float2 hv = *(const float2*)&hB[i*NDIM + t*2];
  float2 bv = *(const float2*)&bias[t*2];
  float2 o;
  o.x = acc.x + sn*hv.x + bv.x;
  o.y = acc.y + sn*hv.y + bv.y;
  *(float2*)&hC[i*NDIM + t*2] = o;
}

// ---- BN column stats (sum, sumsq) ----
__global__ void stats_k(const float* __restrict__ h, float* __restrict__ sums,
                        float* __restrict__ sumsq, int N){
  __shared__ float ls[256], lq[256];
  int t = threadIdx.x;
  int f = t & 127, half = t >> 7;
  int rowsPerBlock = (N + gridDim.x - 1)/gridDim.x;
  int r0 = blockIdx.x * rowsPerBlock;
  int r1 = min(N, r0 + rowsPerBlock);
  float s=0.f, q=0.f;
  for(int r=r0+half; r<r1; r+=2){
    float v = h[r*NDIM + f];
    s += v; q += v*v;
  }
  ls[t]=s; lq[t]=q; __syncthreads();
  if(t < 128){
    s = ls[t] + ls[t+128];
    q = lq[t] + lq[t+128];
    atomicAdd(&sums[f], s);
    atomicAdd(&sumsq[f], q);
  }
}

// ---- BN finalize: per-feature scale/shift so bn_sigmoid(v) = sigmoid(v*scale+shift) ----
__global__ void finalize_k(const float* __restrict__ sums, const float* __restrict__ sumsq,
                           const float* __restrict__ g, const float* __restrict__ be,
                           float* __restrict__ scale, float* __restrict__ shift, int N){
  int f = threadIdx.x;   // 128
  float invN = 1.0f/(float)N;
  float m = sums[f]*invN;
  float var = fmaxf(sumsq[f]*invN - m*m, 0.f);
  float s = g[f]*rsqrtf(var + 1e-5f);
  scale[f] = s;
  shift[f] = be[f] - m*s;
}

// ---- pooling: per-graph contiguous mean of sigmoid(v*scale+shift), no atomics ----
__global__ __launch_bounds__(512) void pool_k(const float* __restrict__ hC,
                                              const int* __restrict__ bound,
                                              const float* __restrict__ scale,
                                              const float* __restrict__ shift,
                                              float* __restrict__ out){
  __shared__ float lds[512];
  int g = blockIdx.x;
  int t = threadIdx.x;
  int f = t & 127, quarter = t >> 7;       // 4 row-groups
  int r0 = bound[g], r1 = bound[g+1];
  float sc = scale[f], sh = shift[f];
  float acc = 0.f;
  for(int r = r0 + quarter; r < r1; r += 4)
    acc += sigmoidf_(hC[r*NDIM + f]*sc + sh);
  lds[t] = acc; __syncthreads();
  if(t < 128){
    acc = lds[t] + lds[t+128] + lds[t+256] + lds[t+384];
    float cnt = (float)(r1 - r0);
    out[g*NDIM + f] = acc / fmaxf(cnt, 1.0f);
  }
}

extern "C" void kernel_launch(void* const* d_in, const int* in_sizes, int n_in,
                              void* d_out, int out_size, void* d_ws, size_t ws_size,
                              hipStream_t stream){
  const float* x     = (const float*)d_in[0];
  const int*   ei    = (const int*)d_in[1];
  const int*   batch = (const int*)d_in[3];
  const float* W [3] = {(const float*)d_in[4], (const float*)d_in[6], (const float*)d_in[8]};
  const float* bi[3] = {(const float*)d_in[5], (const float*)d_in[7], (const float*)d_in[9]};
  const float* gg[3] = {(const float*)d_in[10], (const float*)d_in[12], (const float*)d_in[14]};
  const float* bb[3] = {(const float*)d_in[11], (const float*)d_in[13], (const float*)d_in[15]};

  int N = in_sizes[0] / NDIM;
  int E = in_sizes[1] / 2;
  int G = out_size / NDIM;
  const int* src = ei;
  const int* dst = ei + E;

  // workspace bump allocator (256 B aligned)
  char* p = (char*)d_ws;
  auto alloc = [&](size_t bytes)->void*{
    void* r = (void*)p; p += (bytes + 255) & ~(size_t)255; return r;
  };
  float* hB        = (float*)alloc((size_t)N*NDIM*4);
  float* hC        = (float*)alloc((size_t)N*NDIM*4);
  int*   counts    = (int*)  alloc((size_t)N*4);
  int*   cursor    = (int*)  alloc((size_t)N*4);
  int*   scanned   = (int*)  alloc((size_t)N*4);
  int*   chunksums = (int*)  alloc(256*4);
  int*   row_start = (int*)  alloc((size_t)N*4);
  float* dinv      = (float*)alloc((size_t)N*4);
  int*   csr_src   = (int*)  alloc((size_t)E*4);
  float* csr_norm  = (float*)alloc((size_t)E*4);
  float* sums      = (float*)alloc(3*128*4);
  float* sumsq     = (float*)alloc(3*128*4);
  float* scale     = (float*)alloc(3*128*4);
  float* shift     = (float*)alloc(3*128*4);
  int*   bound     = (int*)  alloc(256*4);

  hipMemsetAsync(counts, 0, (size_t)N*4, stream);
  hipMemsetAsync(cursor, 0, (size_t)N*4, stream);
  hipMemsetAsync(sums,  0, 3*128*4, stream);
  hipMemsetAsync(sumsq, 0, 3*128*4, stream);

  deg_count_k<<<(E+255)/256, 256, 0, stream>>>(dst, counts, E);
  dinv_k<<<(N+255)/256, 256, 0, stream>>>(counts, dinv, N);

  int nchunks = (N+255)/256;     // 196 <= 256
  scan1_k<<<nchunks, 256, 0, stream>>>(counts, scanned, chunksums, N);
  scan2_k<<<1, 256, 0, stream>>>(chunksums, nchunks);
  scan3_k<<<(N+255)/256, 256, 0, stream>>>(scanned, counts, chunksums, row_start, N);
  fill_k<<<(E+255)/256, 256, 0, stream>>>(src, dst, dinv, row_start, cursor, csr_src, csr_norm, E);
  bounds_k<<<1, 128, 0, stream>>>(batch, bound, N, G);

  const float* hin = x;
  for(int l=0; l<3; l++){
    const float* sc = (l == 0) ? nullptr : (scale + (l-1)*128);
    const float* sh = (l == 0) ? nullptr : (shift + (l-1)*128);
    gemm_k<<<(N+GEMM_TM-1)/GEMM_TM, 256, 0, stream>>>(hin, W[l], hB, sc, sh, N);
    agg_k<<<N, 64, 0, stream>>>(hB, dinv, row_start, counts, csr_src, csr_norm, bi[l], hC, N);
    stats_k<<<128, 256, 0, stream>>>(hC, sums + l*128, sumsq + l*128, N);
    finalize_k<<<1, 128, 0, stream>>>(sums + l*128, sumsq + l*128, gg[l], bb[l],
                                      scale + l*128, shift + l*128, N);
    hin = hC;
  }

  pool_k<<<G, 512, 0, stream>>>(hC, bound, scale + 2*128, shift + 2*128, (float*)d_out);
}

// Round 3
// 652.832 us; speedup vs baseline: 1.5893x; 1.2320x over previous
//
#include <hip/hip_runtime.h>
#include <math.h>

#define NDIM 128      // feature dim (D == H == 128)
#define GEMM_TM 64    // rows per block in GEMM
#define KT 32         // k-tile in GEMM

__device__ __forceinline__ float sigmoidf_(float x){ return 1.0f/(1.0f + __expf(-x)); }

// f32 -> bf16 (round-to-nearest-even), manual to avoid header quirks
__device__ __forceinline__ unsigned short f2bf(float f){
  unsigned u = __float_as_uint(f);
  unsigned r = (u + 0x7fffu + ((u >> 16) & 1u)) >> 16;
  return (unsigned short)r;
}

// ---- degree / normalization ----
__global__ void deg_count_k(const int* __restrict__ dst, int* __restrict__ counts, int E){
  int e = blockIdx.x*blockDim.x + threadIdx.x;
  if(e < E) atomicAdd(&counts[dst[e]], 1);
}

__global__ void dinv_k(const int* __restrict__ counts, float* __restrict__ dinv, int N){
  int i = blockIdx.x*blockDim.x + threadIdx.x;
  if(i < N) dinv[i] = rsqrtf(1.0f + (float)counts[i]);
}

// ---- 3-kernel exclusive prefix scan over counts (chunk = 256) ----
__global__ void scan1_k(const int* __restrict__ counts, int* __restrict__ scanned,
                        int* __restrict__ chunksums, int N){
  __shared__ int lds[256];
  int t = threadIdx.x; int idx = blockIdx.x*256 + t;
  int x = (idx < N) ? counts[idx] : 0;
  lds[t] = x; __syncthreads();
  for(int o=1;o<256;o<<=1){
    int v = (t>=o) ? lds[t-o] : 0;
    __syncthreads();
    lds[t] += v;
    __syncthreads();
  }
  if(idx < N) scanned[idx] = lds[t];
  if(t == 255) chunksums[blockIdx.x] = lds[255];
}

__global__ void scan2_k(int* __restrict__ chunksums, int nchunks){
  __shared__ int lds[256];
  int t = threadIdx.x;
  int x = (t < nchunks) ? chunksums[t] : 0;
  lds[t] = x; __syncthreads();
  for(int o=1;o<256;o<<=1){
    int v = (t>=o) ? lds[t-o] : 0;
    __syncthreads();
    lds[t] += v;
    __syncthreads();
  }
  if(t < nchunks) chunksums[t] = lds[t] - x;   // exclusive
}

__global__ void scan3_k(const int* __restrict__ scanned, const int* __restrict__ counts,
                        const int* __restrict__ chunksums, int* __restrict__ row_start, int N){
  int i = blockIdx.x*blockDim.x + threadIdx.x;
  if(i < N) row_start[i] = scanned[i] - counts[i] + chunksums[i>>8];
}

__global__ void fill_k(const int* __restrict__ src, const int* __restrict__ dst,
                       const float* __restrict__ dinv, const int* __restrict__ row_start,
                       int* __restrict__ cursor, int* __restrict__ csr_src,
                       float* __restrict__ csr_norm, int E){
  int e = blockIdx.x*blockDim.x + threadIdx.x;
  if(e >= E) return;
  int d = dst[e], s = src[e];
  int pos = row_start[d] + atomicAdd(&cursor[d], 1);
  csr_src[pos] = s;
  csr_norm[pos] = dinv[s]*dinv[d];
}

// ---- graph boundaries via binary search (batch is sorted) ----
__global__ void bounds_k(const int* __restrict__ batch, int* __restrict__ bound, int N, int G){
  int g = threadIdx.x;
  if(g > G) return;
  int lo = 0, hi = N;
  while(lo < hi){ int mid = (lo+hi)>>1; if(batch[mid] < g) lo = mid+1; else hi = mid; }
  bound[g] = lo;
}

// ---- dense GEMM: Bh[N,128](bf16) = bnsig(A)[N,128] @ W[128,128] ----
__global__ __launch_bounds__(256) void gemm_k(const float* __restrict__ A,
                                              const float* __restrict__ W,
                                              unsigned short* __restrict__ Bh,
                                              const float* __restrict__ scale,  // null => raw A
                                              const float* __restrict__ shift,
                                              int N){
  __shared__ float Wl[KT][NDIM];      // 16 KB
  __shared__ float Hl[GEMM_TM][KT];   // 8 KB
  int t = threadIdx.x;
  int row0 = blockIdx.x * GEMM_TM;
  int colg = (t & 31) * 4;            // 4 consecutive output cols
  int rowg = (t >> 5) * 8;            // 8 rows per thread
  bool bn = (scale != nullptr);
  float acc[8][4];
  #pragma unroll
  for(int r=0;r<8;r++)
    #pragma unroll
    for(int c=0;c<4;c++) acc[r][c]=0.f;

  for(int k0=0;k0<NDIM;k0+=KT){
    #pragma unroll
    for(int i=0;i<4;i++){             // W tile: 4096 floats
      int lin = (t + i*256)*4;
      int kk = lin >> 7, col = lin & 127;
      *(float4*)&Wl[kk][col] = *(const float4*)&W[(k0+kk)*NDIM + col];
    }
    #pragma unroll
    for(int i=0;i<2;i++){             // H tile: 2048 floats
      int lin = (t + i*256)*4;
      int r = lin >> 5, kk = lin & 31;
      int grow = row0 + r;
      float4 v = make_float4(0.f,0.f,0.f,0.f);
      if(grow < N){
        v = *(const float4*)&A[grow*NDIM + k0 + kk];
        if(bn){
          float4 sc = *(const float4*)&scale[k0+kk];
          float4 sh = *(const float4*)&shift[k0+kk];
          v.x = sigmoidf_(v.x*sc.x + sh.x);
          v.y = sigmoidf_(v.y*sc.y + sh.y);
          v.z = sigmoidf_(v.z*sc.z + sh.z);
          v.w = sigmoidf_(v.w*sc.w + sh.w);
        }
      }
      *(float4*)&Hl[r][kk] = v;
    }
    __syncthreads();
    #pragma unroll
    for(int kk=0; kk<KT; kk+=4){
      float4 wv0 = *(float4*)&Wl[kk+0][colg];
      float4 wv1 = *(float4*)&Wl[kk+1][colg];
      float4 wv2 = *(float4*)&Wl[kk+2][colg];
      float4 wv3 = *(float4*)&Wl[kk+3][colg];
      #pragma unroll
      for(int r=0;r<8;r++){
        float4 hv = *(float4*)&Hl[rowg + r][kk];
        acc[r][0] += hv.x*wv0.x + hv.y*wv1.x + hv.z*wv2.x + hv.w*wv3.x;
        acc[r][1] += hv.x*wv0.y + hv.y*wv1.y + hv.z*wv2.y + hv.w*wv3.y;
        acc[r][2] += hv.x*wv0.z + hv.y*wv1.z + hv.z*wv2.z + hv.w*wv3.z;
        acc[r][3] += hv.x*wv0.w + hv.y*wv1.w + hv.z*wv2.w + hv.w*wv3.w;
      }
    }
    __syncthreads();
  }
  #pragma unroll
  for(int r=0;r<8;r++){
    int grow = row0 + rowg + r;
    if(grow < N){
      ushort4 o;
      o.x = f2bf(acc[r][0]); o.y = f2bf(acc[r][1]);
      o.z = f2bf(acc[r][2]); o.w = f2bf(acc[r][3]);
      *(ushort4*)&Bh[grow*NDIM + colg] = o;
    }
  }
}

// ---- CSR gather aggregation (bf16 rows): hC[i] = sum_e norm*hB[src] + dinv^2*hB[i] + b ----
__global__ void agg_k(const unsigned int* __restrict__ hb,   // bf16x2 packed, N x 64
                      const float* __restrict__ dinv,
                      const int* __restrict__ row_start, const int* __restrict__ counts,
                      const int* __restrict__ csr_src, const float* __restrict__ csr_norm,
                      const float* __restrict__ bias, float* __restrict__ hC, int N){
  int i = blockIdx.x;
  if(i >= N) return;
  int t = threadIdx.x;                // 64 threads, lane = feature pair
  int rs = row_start[i], cnt = counts[i];
  float2 acc = make_float2(0.f, 0.f);
  int j = rs;
  for(; j+1 < rs+cnt; j += 2){        // 2-way unroll: overlap the two row loads
    int s0 = csr_src[j],   s1 = csr_src[j+1];
    float n0 = csr_norm[j], n1 = csr_norm[j+1];
    unsigned u0 = hb[s0*64 + t];
    unsigned u1 = hb[s1*64 + t];
    acc.x += n0*__uint_as_float(u0<<16) + n1*__uint_as_float(u1<<16);
    acc.y += n0*__uint_as_float(u0 & 0xffff0000u) + n1*__uint_as_float(u1 & 0xffff0000u);
  }
  if(j < rs+cnt){
    int s = csr_src[j]; float nm = csr_norm[j];
    unsigned u = hb[s*64 + t];
    acc.x += nm*__uint_as_float(u<<16);
    acc.y += nm*__uint_as_float(u & 0xffff0000u);
  }
  float di = dinv[i]; float sn = di*di;
  unsigned su = hb[i*64 + t];
  float2 bv = *(const float2*)&bias[t*2];
  float2 o;
  o.x = acc.x + sn*__uint_as_float(su<<16)          + bv.x;
  o.y = acc.y + sn*__uint_as_float(su & 0xffff0000u) + bv.y;
  *(float2*)&hC[i*NDIM + t*2] = o;
}

// ---- BN column stats (sum, sumsq) ----
__global__ void stats_k(const float* __restrict__ h, float* __restrict__ sums,
                        float* __restrict__ sumsq, int N){
  __shared__ float ls[256], lq[256];
  int t = threadIdx.x;
  int f = t & 127, half = t >> 7;
  int rowsPerBlock = (N + gridDim.x - 1)/gridDim.x;
  int r0 = blockIdx.x * rowsPerBlock;
  int r1 = min(N, r0 + rowsPerBlock);
  float s=0.f, q=0.f;
  for(int r=r0+half; r<r1; r+=2){
    float v = h[r*NDIM + f];
    s += v; q += v*v;
  }
  ls[t]=s; lq[t]=q; __syncthreads();
  if(t < 128){
    s = ls[t] + ls[t+128];
    q = lq[t] + lq[t+128];
    atomicAdd(&sums[f], s);
    atomicAdd(&sumsq[f], q);
  }
}

// ---- BN finalize: per-feature scale/shift so bn_sigmoid(v) = sigmoid(v*scale+shift) ----
__global__ void finalize_k(const float* __restrict__ sums, const float* __restrict__ sumsq,
                           const float* __restrict__ g, const float* __restrict__ be,
                           float* __restrict__ scale, float* __restrict__ shift, int N){
  int f = threadIdx.x;   // 128
  float invN = 1.0f/(float)N;
  float m = sums[f]*invN;
  float var = fmaxf(sumsq[f]*invN - m*m, 0.f);
  float s = g[f]*rsqrtf(var + 1e-5f);
  scale[f] = s;
  shift[f] = be[f] - m*s;
}

// ---- pooling phase 1: chunked segment-sum of sigmoid(v*scale+shift), atomics at flushes ----
#define PCH 128
__global__ __launch_bounds__(256) void pool_k(const float* __restrict__ hC,
                                              const int* __restrict__ batch,
                                              const float* __restrict__ scale,
                                              const float* __restrict__ shift,
                                              float* __restrict__ out, int N){
  int t = threadIdx.x;
  int f = t & 127, half = t >> 7;
  int r0 = blockIdx.x*PCH + half;
  int r1 = min(N, blockIdx.x*PCH + PCH);
  float sc = scale[f], sh = shift[f];
  float acc = 0.f; int cur = -1;
  for(int r = r0; r < r1; r += 2){
    int g = batch[r];
    if(g != cur){
      if(cur >= 0) atomicAdd(&out[cur*NDIM + f], acc);
      acc = 0.f; cur = g;
    }
    acc += sigmoidf_(hC[r*NDIM + f]*sc + sh);
  }
  if(cur >= 0) atomicAdd(&out[cur*NDIM + f], acc);
}

// ---- pooling phase 2: divide by graph size ----
__global__ void div_k(float* __restrict__ out, const int* __restrict__ bound){
  int g = blockIdx.x, f = threadIdx.x;
  float cnt = (float)(bound[g+1] - bound[g]);
  out[g*NDIM + f] /= fmaxf(cnt, 1.0f);
}

extern "C" void kernel_launch(void* const* d_in, const int* in_sizes, int n_in,
                              void* d_out, int out_size, void* d_ws, size_t ws_size,
                              hipStream_t stream){
  const float* x     = (const float*)d_in[0];
  const int*   ei    = (const int*)d_in[1];
  const int*   batch = (const int*)d_in[3];
  const float* W [3] = {(const float*)d_in[4], (const float*)d_in[6], (const float*)d_in[8]};
  const float* bi[3] = {(const float*)d_in[5], (const float*)d_in[7], (const float*)d_in[9]};
  const float* gg[3] = {(const float*)d_in[10], (const float*)d_in[12], (const float*)d_in[14]};
  const float* bb[3] = {(const float*)d_in[11], (const float*)d_in[13], (const float*)d_in[15]};

  int N = in_sizes[0] / NDIM;
  int E = in_sizes[1] / 2;
  int G = out_size / NDIM;
  const int* src = ei;
  const int* dst = ei + E;

  // workspace bump allocator (256 B aligned)
  char* p = (char*)d_ws;
  auto alloc = [&](size_t bytes)->void*{
    void* r = (void*)p; p += (bytes + 255) & ~(size_t)255; return r;
  };
  unsigned short* hB = (unsigned short*)alloc((size_t)N*NDIM*2);   // bf16
  float* hC        = (float*)alloc((size_t)N*NDIM*4);
  int*   counts    = (int*)  alloc((size_t)N*4);
  int*   cursor    = (int*)  alloc((size_t)N*4);
  int*   scanned   = (int*)  alloc((size_t)N*4);
  int*   chunksums = (int*)  alloc(256*4);
  int*   row_start = (int*)  alloc((size_t)N*4);
  float* dinv      = (float*)alloc((size_t)N*4);
  int*   csr_src   = (int*)  alloc((size_t)E*4);
  float* csr_norm  = (float*)alloc((size_t)E*4);
  float* sums      = (float*)alloc(3*128*4);
  float* sumsq     = (float*)alloc(3*128*4);
  float* scale     = (float*)alloc(3*128*4);
  float* shift     = (float*)alloc(3*128*4);
  int*   bound     = (int*)  alloc(256*4);

  hipMemsetAsync(counts, 0, (size_t)N*4, stream);
  hipMemsetAsync(cursor, 0, (size_t)N*4, stream);
  hipMemsetAsync(sums,  0, 3*128*4, stream);
  hipMemsetAsync(sumsq, 0, 3*128*4, stream);
  hipMemsetAsync(d_out, 0, (size_t)out_size*4, stream);

  deg_count_k<<<(E+255)/256, 256, 0, stream>>>(dst, counts, E);
  dinv_k<<<(N+255)/256, 256, 0, stream>>>(counts, dinv, N);

  int nchunks = (N+255)/256;     // 196 <= 256
  scan1_k<<<nchunks, 256, 0, stream>>>(counts, scanned, chunksums, N);
  scan2_k<<<1, 256, 0, stream>>>(chunksums, nchunks);
  scan3_k<<<(N+255)/256, 256, 0, stream>>>(scanned, counts, chunksums, row_start, N);
  fill_k<<<(E+255)/256, 256, 0, stream>>>(src, dst, dinv, row_start, cursor, csr_src, csr_norm, E);
  bounds_k<<<1, 128, 0, stream>>>(batch, bound, N, G);

  const float* hin = x;
  for(int l=0; l<3; l++){
    const float* sc = (l == 0) ? nullptr : (scale + (l-1)*128);
    const float* sh = (l == 0) ? nullptr : (shift + (l-1)*128);
    gemm_k<<<(N+GEMM_TM-1)/GEMM_TM, 256, 0, stream>>>(hin, W[l], hB, sc, sh, N);
    agg_k<<<N, 64, 0, stream>>>((const unsigned int*)hB, dinv, row_start, counts,
                                csr_src, csr_norm, bi[l], hC, N);
    stats_k<<<400, 256, 0, stream>>>(hC, sums + l*128, sumsq + l*128, N);
    finalize_k<<<1, 128, 0, stream>>>(sums + l*128, sumsq + l*128, gg[l], bb[l],
                                      scale + l*128, shift + l*128, N);
    hin = hC;
  }

  pool_k<<<(N+PCH-1)/PCH, 256, 0, stream>>>(hC, batch, scale + 2*128, shift + 2*128,
                                            (float*)d_out, N);
  div_k<<<G, 128, 0, stream>>>((float*)d_out, bound);
}

// Round 4
// 499.320 us; speedup vs baseline: 2.0779x; 1.3074x over previous
//
#include <hip/hip_runtime.h>
#include <math.h>

#define NDIM 128      // feature dim (D == H == 128)

typedef __attribute__((ext_vector_type(8))) short short8;
typedef __attribute__((ext_vector_type(4))) float f32x4;

__device__ __forceinline__ float sigmoidf_(float x){ return 1.0f/(1.0f + __expf(-x)); }

// f32 -> bf16 (round-to-nearest-even)
__device__ __forceinline__ unsigned short f2bf(float f){
  unsigned u = __float_as_uint(f);
  unsigned r = (u + 0x7fffu + ((u >> 16) & 1u)) >> 16;
  return (unsigned short)r;
}

// ---- degree / normalization ----
__global__ void deg_count_k(const int* __restrict__ dst, int* __restrict__ counts, int E){
  int e = blockIdx.x*blockDim.x + threadIdx.x;
  if(e < E) atomicAdd(&counts[dst[e]], 1);
}

__global__ void dinv_k(const int* __restrict__ counts, float* __restrict__ dinv, int N){
  int i = blockIdx.x*blockDim.x + threadIdx.x;
  if(i < N) dinv[i] = rsqrtf(1.0f + (float)counts[i]);
}

// ---- 3-kernel exclusive prefix scan over counts (chunk = 256) ----
__global__ void scan1_k(const int* __restrict__ counts, int* __restrict__ scanned,
                        int* __restrict__ chunksums, int N){
  __shared__ int lds[256];
  int t = threadIdx.x; int idx = blockIdx.x*256 + t;
  int x = (idx < N) ? counts[idx] : 0;
  lds[t] = x; __syncthreads();
  for(int o=1;o<256;o<<=1){
    int v = (t>=o) ? lds[t-o] : 0;
    __syncthreads();
    lds[t] += v;
    __syncthreads();
  }
  if(idx < N) scanned[idx] = lds[t];
  if(t == 255) chunksums[blockIdx.x] = lds[255];
}

__global__ void scan2_k(int* __restrict__ chunksums, int nchunks){
  __shared__ int lds[256];
  int t = threadIdx.x;
  int x = (t < nchunks) ? chunksums[t] : 0;
  lds[t] = x; __syncthreads();
  for(int o=1;o<256;o<<=1){
    int v = (t>=o) ? lds[t-o] : 0;
    __syncthreads();
    lds[t] += v;
    __syncthreads();
  }
  if(t < nchunks) chunksums[t] = lds[t] - x;   // exclusive
}

__global__ void scan3_k(const int* __restrict__ scanned, const int* __restrict__ counts,
                        const int* __restrict__ chunksums, int* __restrict__ row_start, int N){
  int i = blockIdx.x*blockDim.x + threadIdx.x;
  if(i < N) row_start[i] = scanned[i] - counts[i] + chunksums[i>>8];
}

__global__ void fill_k(const int* __restrict__ src, const int* __restrict__ dst,
                       const float* __restrict__ dinv, const int* __restrict__ row_start,
                       int* __restrict__ cursor, int* __restrict__ csr_src,
                       float* __restrict__ csr_norm, int E){
  int e = blockIdx.x*blockDim.x + threadIdx.x;
  if(e >= E) return;
  int d = dst[e], s = src[e];
  int pos = row_start[d] + atomicAdd(&cursor[d], 1);
  csr_src[pos] = s;
  csr_norm[pos] = dinv[s]*dinv[d];
}

// ---- graph boundaries via binary search (batch is sorted) ----
__global__ void bounds_k(const int* __restrict__ batch, int* __restrict__ bound, int N, int G){
  int g = threadIdx.x;
  if(g > G) return;
  int lo = 0, hi = N;
  while(lo < hi){ int mid = (lo+hi)>>1; if(batch[mid] < g) lo = mid+1; else hi = mid; }
  bound[g] = lo;
}

// ---- W prep: f32 [k][n] -> bf16 swizzled [(k>>3)*128+n][k&7], all 3 layers ----
__global__ void wprep_k(const float* __restrict__ W0, const float* __restrict__ W1,
                        const float* __restrict__ W2, unsigned short* __restrict__ Wsw){
  int t = blockIdx.x*256 + threadIdx.x;
  if(t >= 3*16384) return;
  int l = t >> 14; int i = t & 16383;
  const float* W = (l==0) ? W0 : ((l==1) ? W1 : W2);
  int k = i >> 7, n = i & 127;
  Wsw[l*16384 + (((k>>3)*128 + n)<<3) + (k&7)] = f2bf(W[k*128+n]);
}

// ---- MFMA GEMM: Bh[N,128](bf16) = bnsig(A)[N,128] @ W[128,128] ----
// A staged to LDS as bf16, k-packed: Al[((k>>3)*128 + r)*8 + (k&7)]
// W already swizzled identically. Block tile 128x128, 4 waves 2x2, 64x64/wave.
__global__ __launch_bounds__(256) void gemm_mfma_k(const float* __restrict__ A,
                                                   const unsigned short* __restrict__ Wsw,
                                                   unsigned short* __restrict__ Bh,
                                                   const float* __restrict__ scale,
                                                   const float* __restrict__ shift,
                                                   int N){
  __shared__ unsigned short Al[16384];   // 32 KB
  __shared__ unsigned short Wl[16384];   // 32 KB  (total 64 KB -> 2 blocks/CU)
  int t = threadIdx.x;
  int row0 = blockIdx.x * 128;
  bool bn = (scale != nullptr);

  // stage W: 2048 x 16B coalesced copies
  #pragma unroll
  for(int i=0;i<8;i++){
    int u = t + i*256;                   // 16B-unit index
    *(uint4*)&Wl[u<<3] = *(const uint4*)&Wsw[u<<3];
  }
  // stage A: fused BN+sigmoid + bf16 pack; o = k-octet (coalesced global reads)
  int o = t & 15, rbase = t >> 4;        // 16 rows per iter
  #pragma unroll
  for(int it=0; it<8; it++){
    int r = rbase + it*16;
    int grow = row0 + r;
    float4 v0 = make_float4(0.f,0.f,0.f,0.f), v1 = v0;
    if(grow < N){
      v0 = *(const float4*)&A[grow*NDIM + o*8];
      v1 = *(const float4*)&A[grow*NDIM + o*8 + 4];
      if(bn){
        float4 sc0 = *(const float4*)&scale[o*8],   sh0 = *(const float4*)&shift[o*8];
        float4 sc1 = *(const float4*)&scale[o*8+4], sh1 = *(const float4*)&shift[o*8+4];
        v0.x = sigmoidf_(v0.x*sc0.x + sh0.x); v0.y = sigmoidf_(v0.y*sc0.y + sh0.y);
        v0.z = sigmoidf_(v0.z*sc0.z + sh0.z); v0.w = sigmoidf_(v0.w*sc0.w + sh0.w);
        v1.x = sigmoidf_(v1.x*sc1.x + sh1.x); v1.y = sigmoidf_(v1.y*sc1.y + sh1.y);
        v1.z = sigmoidf_(v1.z*sc1.z + sh1.z); v1.w = sigmoidf_(v1.w*sc1.w + sh1.w);
      }
    }
    uint4 pk;
    pk.x = (unsigned)f2bf(v0.x) | ((unsigned)f2bf(v0.y)<<16);
    pk.y = (unsigned)f2bf(v0.z) | ((unsigned)f2bf(v0.w)<<16);
    pk.z = (unsigned)f2bf(v1.x) | ((unsigned)f2bf(v1.y)<<16);
    pk.w = (unsigned)f2bf(v1.z) | ((unsigned)f2bf(v1.w)<<16);
    *(uint4*)&Al[(o*128 + r)<<3] = pk;
  }
  __syncthreads();

  int wv = t >> 6, lane = t & 63, quad = lane >> 4, l16 = lane & 15;
  int rw = (wv & 1) * 64, cw = (wv >> 1) * 64;
  f32x4 acc[4][4];
  #pragma unroll
  for(int rt=0;rt<4;rt++)
    #pragma unroll
    for(int ct=0;ct<4;ct++) acc[rt][ct] = (f32x4){0.f,0.f,0.f,0.f};

  #pragma unroll
  for(int ks=0; ks<4; ks++){
    short8 a[4], b[4];
    #pragma unroll
    for(int rt=0;rt<4;rt++)
      a[rt] = *(short8*)&Al[(((ks*4+quad)*128) + rw + rt*16 + l16) << 3];
    #pragma unroll
    for(int ct=0;ct<4;ct++)
      b[ct] = *(short8*)&Wl[(((ks*4+quad)*128) + cw + ct*16 + l16) << 3];
    #pragma unroll
    for(int rt=0;rt<4;rt++)
      #pragma unroll
      for(int ct=0;ct<4;ct++)
        acc[rt][ct] = __builtin_amdgcn_mfma_f32_16x16x32_bf16(a[rt], b[ct], acc[rt][ct], 0, 0, 0);
  }

  // epilogue: C/D layout col=lane&15, row=quad*4+reg
  #pragma unroll
  for(int rt=0;rt<4;rt++){
    int gr = row0 + rw + rt*16 + quad*4;
    #pragma unroll
    for(int ct=0;ct<4;ct++){
      int col = cw + ct*16 + l16;
      #pragma unroll
      for(int reg=0;reg<4;reg++){
        if(gr + reg < N) Bh[(gr+reg)*NDIM + col] = f2bf(acc[rt][ct][reg]);
      }
    }
  }
}

// ---- CSR gather aggregation (bf16 rows): hC[i] = sum_e norm*hB[src] + dinv^2*hB[i] + b ----
__global__ void agg_k(const unsigned int* __restrict__ hb,   // bf16x2 packed, N x 64
                      const float* __restrict__ dinv,
                      const int* __restrict__ row_start, const int* __restrict__ counts,
                      const int* __restrict__ csr_src, const float* __restrict__ csr_norm,
                      const float* __restrict__ bias, float* __restrict__ hC, int N){
  int i = blockIdx.x;
  if(i >= N) return;
  int t = threadIdx.x;                // 64 threads, lane = feature pair
  int rs = row_start[i], cnt = counts[i];
  float2 acc = make_float2(0.f, 0.f);
  int j = rs;
  for(; j+1 < rs+cnt; j += 2){
    int s0 = csr_src[j],   s1 = csr_src[j+1];
    float n0 = csr_norm[j], n1 = csr_norm[j+1];
    unsigned u0 = hb[s0*64 + t];
    unsigned u1 = hb[s1*64 + t];
    acc.x += n0*__uint_as_float(u0<<16) + n1*__uint_as_float(u1<<16);
    acc.y += n0*__uint_as_float(u0 & 0xffff0000u) + n1*__uint_as_float(u1 & 0xffff0000u);
  }
  if(j < rs+cnt){
    int s = csr_src[j]; float nm = csr_norm[j];
    unsigned u = hb[s*64 + t];
    acc.x += nm*__uint_as_float(u<<16);
    acc.y += nm*__uint_as_float(u & 0xffff0000u);
  }
  float di = dinv[i]; float sn = di*di;
  unsigned su = hb[i*64 + t];
  float2 bv = *(const float2*)&bias[t*2];
  float2 o;
  o.x = acc.x + sn*__uint_as_float(su<<16)           + bv.x;
  o.y = acc.y + sn*__uint_as_float(su & 0xffff0000u) + bv.y;
  *(float2*)&hC[i*NDIM + t*2] = o;
}

// ---- BN column stats (sum, sumsq) ----
__global__ void stats_k(const float* __restrict__ h, float* __restrict__ sums,
                        float* __restrict__ sumsq, int N){
  __shared__ float ls[256], lq[256];
  int t = threadIdx.x;
  int f = t & 127, half = t >> 7;
  int rowsPerBlock = (N + gridDim.x - 1)/gridDim.x;
  int r0 = blockIdx.x * rowsPerBlock;
  int r1 = min(N, r0 + rowsPerBlock);
  float s=0.f, q=0.f;
  for(int r=r0+half; r<r1; r+=2){
    float v = h[r*NDIM + f];
    s += v; q += v*v;
  }
  ls[t]=s; lq[t]=q; __syncthreads();
  if(t < 128){
    s = ls[t] + ls[t+128];
    q = lq[t] + lq[t+128];
    atomicAdd(&sums[f], s);
    atomicAdd(&sumsq[f], q);
  }
}

// ---- BN finalize: per-feature scale/shift so bn_sigmoid(v) = sigmoid(v*scale+shift) ----
__global__ void finalize_k(const float* __restrict__ sums, const float* __restrict__ sumsq,
                           const float* __restrict__ g, const float* __restrict__ be,
                           float* __restrict__ scale, float* __restrict__ shift, int N){
  int f = threadIdx.x;   // 128
  float invN = 1.0f/(float)N;
  float m = sums[f]*invN;
  float var = fmaxf(sumsq[f]*invN - m*m, 0.f);
  float s = g[f]*rsqrtf(var + 1e-5f);
  scale[f] = s;
  shift[f] = be[f] - m*s;
}

// ---- pooling phase 1: chunked segment-sum of sigmoid(v*scale+shift) ----
#define PCH 128
__global__ __launch_bounds__(256) void pool_k(const float* __restrict__ hC,
                                              const int* __restrict__ batch,
                                              const float* __restrict__ scale,
                                              const float* __restrict__ shift,
                                              float* __restrict__ out, int N){
  int t = threadIdx.x;
  int f = t & 127, half = t >> 7;
  int r0 = blockIdx.x*PCH + half;
  int r1 = min(N, blockIdx.x*PCH + PCH);
  float sc = scale[f], sh = shift[f];
  float acc = 0.f; int cur = -1;
  for(int r = r0; r < r1; r += 2){
    int g = batch[r];
    if(g != cur){
      if(cur >= 0) atomicAdd(&out[cur*NDIM + f], acc);
      acc = 0.f; cur = g;
    }
    acc += sigmoidf_(hC[r*NDIM + f]*sc + sh);
  }
  if(cur >= 0) atomicAdd(&out[cur*NDIM + f], acc);
}

// ---- pooling phase 2: divide by graph size ----
__global__ void div_k(float* __restrict__ out, const int* __restrict__ bound){
  int g = blockIdx.x, f = threadIdx.x;
  float cnt = (float)(bound[g+1] - bound[g]);
  out[g*NDIM + f] /= fmaxf(cnt, 1.0f);
}

extern "C" void kernel_launch(void* const* d_in, const int* in_sizes, int n_in,
                              void* d_out, int out_size, void* d_ws, size_t ws_size,
                              hipStream_t stream){
  const float* x     = (const float*)d_in[0];
  const int*   ei    = (const int*)d_in[1];
  const int*   batch = (const int*)d_in[3];
  const float* W [3] = {(const float*)d_in[4], (const float*)d_in[6], (const float*)d_in[8]};
  const float* bi[3] = {(const float*)d_in[5], (const float*)d_in[7], (const float*)d_in[9]};
  const float* gg[3] = {(const float*)d_in[10], (const float*)d_in[12], (const float*)d_in[14]};
  const float* bb[3] = {(const float*)d_in[11], (const float*)d_in[13], (const float*)d_in[15]};

  int N = in_sizes[0] / NDIM;
  int E = in_sizes[1] / 2;
  int G = out_size / NDIM;
  const int* src = ei;
  const int* dst = ei + E;

  // workspace bump allocator (256 B aligned)
  char* p = (char*)d_ws;
  auto alloc = [&](size_t bytes)->void*{
    void* r = (void*)p; p += (bytes + 255) & ~(size_t)255; return r;
  };
  unsigned short* hB  = (unsigned short*)alloc((size_t)N*NDIM*2);   // bf16
  unsigned short* Wsw = (unsigned short*)alloc(3*16384*2);          // bf16 swizzled weights
  float* hC        = (float*)alloc((size_t)N*NDIM*4);
  int*   counts    = (int*)  alloc((size_t)N*4);
  int*   cursor    = (int*)  alloc((size_t)N*4);
  int*   scanned   = (int*)  alloc((size_t)N*4);
  int*   chunksums = (int*)  alloc(256*4);
  int*   row_start = (int*)  alloc((size_t)N*4);
  float* dinv      = (float*)alloc((size_t)N*4);
  int*   csr_src   = (int*)  alloc((size_t)E*4);
  float* csr_norm  = (float*)alloc((size_t)E*4);
  float* sums      = (float*)alloc(3*128*4);
  float* sumsq     = (float*)alloc(3*128*4);
  float* scale     = (float*)alloc(3*128*4);
  float* shift     = (float*)alloc(3*128*4);
  int*   bound     = (int*)  alloc(256*4);

  hipMemsetAsync(counts, 0, (size_t)N*4, stream);
  hipMemsetAsync(cursor, 0, (size_t)N*4, stream);
  hipMemsetAsync(sums,  0, 3*128*4, stream);
  hipMemsetAsync(sumsq, 0, 3*128*4, stream);
  hipMemsetAsync(d_out, 0, (size_t)out_size*4, stream);

  deg_count_k<<<(E+255)/256, 256, 0, stream>>>(dst, counts, E);
  dinv_k<<<(N+255)/256, 256, 0, stream>>>(counts, dinv, N);

  int nchunks = (N+255)/256;     // 196 <= 256
  scan1_k<<<nchunks, 256, 0, stream>>>(counts, scanned, chunksums, N);
  scan2_k<<<1, 256, 0, stream>>>(chunksums, nchunks);
  scan3_k<<<(N+255)/256, 256, 0, stream>>>(scanned, counts, chunksums, row_start, N);
  fill_k<<<(E+255)/256, 256, 0, stream>>>(src, dst, dinv, row_start, cursor, csr_src, csr_norm, E);
  bounds_k<<<1, 128, 0, stream>>>(batch, bound, N, G);
  wprep_k<<<(3*16384+255)/256, 256, 0, stream>>>(W[0], W[1], W[2], Wsw);

  const float* hin = x;
  for(int l=0; l<3; l++){
    const float* sc = (l == 0) ? nullptr : (scale + (l-1)*128);
    const float* sh = (l == 0) ? nullptr : (shift + (l-1)*128);
    gemm_mfma_k<<<(N+127)/128, 256, 0, stream>>>(hin, Wsw + l*16384, hB, sc, sh, N);
    agg_k<<<N, 64, 0, stream>>>((const unsigned int*)hB, dinv, row_start, counts,
                                csr_src, csr_norm, bi[l], hC, N);
    stats_k<<<400, 256, 0, stream>>>(hC, sums + l*128, sumsq + l*128, N);
    finalize_k<<<1, 128, 0, stream>>>(sums + l*128, sumsq + l*128, gg[l], bb[l],
                                      scale + l*128, shift + l*128, N);
    hin = hC;
  }

  pool_k<<<(N+PCH-1)/PCH, 256, 0, stream>>>(hC, batch, scale + 2*128, shift + 2*128,
                                            (float*)d_out, N);
  div_k<<<G, 128, 0, stream>>>((float*)d_out, bound);
}